// Round 1
// baseline (539.923 us; speedup 1.0000x reference)
//
#include <hip/hip_runtime.h>
#include <math.h>

#define NB 64
#define NC 512
#define NT 1000
#define NH 512
#define TWOC 1024
#define NT4 250   // NT/4 float4 per row

// ---------------- Kernel 1: per-(b,c) mean/std of xs = x0+x1+x2 ----------------
__global__ __launch_bounds__(256) void stats_kernel(const float* __restrict__ x0,
                                                    const float* __restrict__ x1,
                                                    const float* __restrict__ x2,
                                                    float* __restrict__ stats) {
    const int row  = blockIdx.x;          // b*NC + c
    const int tid  = threadIdx.x;
    const int lane = tid & 63;
    const int wave = tid >> 6;

    float s = 0.f, sq = 0.f;
    if (tid < NT4) {
        const int idx = row * NT4 + tid;
        const float4 a = ((const float4*)x0)[idx];
        const float4 d = ((const float4*)x1)[idx];
        const float4 e = ((const float4*)x2)[idx];
        const float v0 = a.x + d.x + e.x;
        const float v1 = a.y + d.y + e.y;
        const float v2 = a.z + d.z + e.z;
        const float v3 = a.w + d.w + e.w;
        s  = v0 + v1 + v2 + v3;
        sq = v0*v0 + v1*v1 + v2*v2 + v3*v3;
    }
    #pragma unroll
    for (int off = 32; off; off >>= 1) {
        s  += __shfl_down(s,  off);
        sq += __shfl_down(sq, off);
    }
    __shared__ float ps[4], pq[4];
    if (lane == 0) { ps[wave] = s; pq[wave] = sq; }
    __syncthreads();
    if (tid == 0) {
        const float S = ps[0] + ps[1] + ps[2] + ps[3];
        const float Q = pq[0] + pq[1] + pq[2] + pq[3];
        const float mean = S / (float)NT;
        const float var  = (Q - S * S / (float)NT) / (float)(NT - 1);
        const float sd   = sqrtf(fmaxf(var, 0.f));
        const int b = row >> 9;
        const int c = row & (NC - 1);
        stats[b * TWOC + c]      = mean;
        stats[b * TWOC + NC + c] = sd;
    }
}

// ---------------- Kernel 2: h = stats@W1^T+b1; s = einsum(bh,kch)+b2; w = softmax_k ----------------
__global__ __launch_bounds__(256) void weights_kernel(const float* __restrict__ stats,
                                                      const float* __restrict__ W1,
                                                      const float* __restrict__ b1,
                                                      const float* __restrict__ W2,
                                                      const float* __restrict__ b2,
                                                      float* __restrict__ wbuf) {
    const int b    = blockIdx.x;
    const int tid  = threadIdx.x;
    const int lane = tid & 63;
    const int wave = tid >> 6;

    __shared__ float sl[TWOC];      // stats row
    __shared__ float hl[NH];        // hidden
    __shared__ float s_l[3 * NC];   // pre-softmax scores

    // stage stats row (1024 floats = 256 float4)
    ((float4*)sl)[tid] = ((const float4*)(stats + b * TWOC))[tid];
    __syncthreads();

    // h[j] = dot(stats_row, W1[j,:]) + b1[j] -- one output per wave-iteration, coalesced W1 row reads
    for (int j = wave; j < NH; j += 4) {
        const float4* wr = (const float4*)(W1 + j * TWOC);
        float acc = 0.f;
        #pragma unroll
        for (int r = 0; r < 4; ++r) {
            const int i4 = r * 64 + lane;
            const float4 wv = wr[i4];
            const float4 sv = ((const float4*)sl)[i4];
            acc += wv.x*sv.x + wv.y*sv.y + wv.z*sv.z + wv.w*sv.w;
        }
        #pragma unroll
        for (int off = 32; off; off >>= 1) acc += __shfl_down(acc, off);
        if (lane == 0) hl[j] = acc + b1[j];
    }
    __syncthreads();

    // s[k,c] = dot(h, W2[k,c,:]) + b2[k,c]
    for (int o = wave; o < 3 * NC; o += 4) {
        const float4* wr = (const float4*)(W2 + (size_t)o * NH);  // o = k*NC + c, W2 flat [(k*NC+c)*NH]
        float acc = 0.f;
        #pragma unroll
        for (int r = 0; r < 2; ++r) {
            const int i4 = r * 64 + lane;
            const float4 wv = wr[i4];
            const float4 hv = ((const float4*)hl)[i4];
            acc += wv.x*hv.x + wv.y*hv.y + wv.z*hv.z + wv.w*hv.w;
        }
        #pragma unroll
        for (int off = 32; off; off >>= 1) acc += __shfl_down(acc, off);
        if (lane == 0) s_l[o] = acc + b2[o];
    }
    __syncthreads();

    // softmax over k (3 branches), write weights
    for (int c = tid; c < NC; c += 256) {
        const float v0 = s_l[c];
        const float v1 = s_l[NC + c];
        const float v2 = s_l[2 * NC + c];
        const float m  = fmaxf(v0, fmaxf(v1, v2));
        const float e0 = expf(v0 - m);
        const float e1 = expf(v1 - m);
        const float e2 = expf(v2 - m);
        const float inv = 1.f / (e0 + e1 + e2);
        wbuf[(b * 3 + 0) * NC + c] = e0 * inv;
        wbuf[(b * 3 + 1) * NC + c] = e1 * inv;
        wbuf[(b * 3 + 2) * NC + c] = e2 * inv;
    }
}

// ---------------- Kernel 3: out = w0*x0 + w1*x1 + w2*x2 ----------------
__global__ __launch_bounds__(256) void apply_kernel(const float* __restrict__ x0,
                                                    const float* __restrict__ x1,
                                                    const float* __restrict__ x2,
                                                    const float* __restrict__ wbuf,
                                                    float* __restrict__ out) {
    const int row = blockIdx.x;           // b*NC + c
    const int tid = threadIdx.x;
    if (tid >= NT4) return;
    const int b = row >> 9;
    const int c = row & (NC - 1);
    const float w0 = wbuf[(b * 3 + 0) * NC + c];
    const float w1 = wbuf[(b * 3 + 1) * NC + c];
    const float w2 = wbuf[(b * 3 + 2) * NC + c];
    const int idx = row * NT4 + tid;
    const float4 a = ((const float4*)x0)[idx];
    const float4 d = ((const float4*)x1)[idx];
    const float4 e = ((const float4*)x2)[idx];
    float4 r;
    r.x = a.x*w0 + d.x*w1 + e.x*w2;
    r.y = a.y*w0 + d.y*w1 + e.y*w2;
    r.z = a.z*w0 + d.z*w1 + e.z*w2;
    r.w = a.w*w0 + d.w*w1 + e.w*w2;
    ((float4*)out)[idx] = r;
}

extern "C" void kernel_launch(void* const* d_in, const int* in_sizes, int n_in,
                              void* d_out, int out_size, void* d_ws, size_t ws_size,
                              hipStream_t stream) {
    const float* x0 = (const float*)d_in[0];
    const float* x1 = (const float*)d_in[1];
    const float* x2 = (const float*)d_in[2];
    const float* W1 = (const float*)d_in[3];
    const float* b1 = (const float*)d_in[4];
    const float* W2 = (const float*)d_in[5];
    const float* b2 = (const float*)d_in[6];
    float* out = (float*)d_out;

    float* stats = (float*)d_ws;                 // NB*TWOC floats
    float* wbuf  = stats + NB * TWOC;            // NB*3*NC floats

    stats_kernel<<<NB * NC, 256, 0, stream>>>(x0, x1, x2, stats);
    weights_kernel<<<NB, 256, 0, stream>>>(stats, W1, b1, W2, b2, wbuf);
    apply_kernel<<<NB * NC, 256, 0, stream>>>(x0, x1, x2, wbuf, out);
}

// Round 2
// 193.948 us; speedup vs baseline: 2.7839x; 2.7839x over previous
//
#include <hip/hip_runtime.h>
#include <math.h>

#define NB 64
#define NC 512
#define NT 1000
#define NH 512
#define TWOC 1024
#define NT4 250   // NT/4 float4 per row

// ---------------- Kernel 1: per-(b,c) mean/std of xs = x0+x1+x2 ----------------
__global__ __launch_bounds__(256) void stats_kernel(const float* __restrict__ x0,
                                                    const float* __restrict__ x1,
                                                    const float* __restrict__ x2,
                                                    float* __restrict__ stats) {
    const int row  = blockIdx.x;          // b*NC + c
    const int tid  = threadIdx.x;
    const int lane = tid & 63;
    const int wave = tid >> 6;

    float s = 0.f, sq = 0.f;
    if (tid < NT4) {
        const int idx = row * NT4 + tid;
        const float4 a = ((const float4*)x0)[idx];
        const float4 d = ((const float4*)x1)[idx];
        const float4 e = ((const float4*)x2)[idx];
        const float v0 = a.x + d.x + e.x;
        const float v1 = a.y + d.y + e.y;
        const float v2 = a.z + d.z + e.z;
        const float v3 = a.w + d.w + e.w;
        s  = v0 + v1 + v2 + v3;
        sq = v0*v0 + v1*v1 + v2*v2 + v3*v3;
    }
    #pragma unroll
    for (int off = 32; off; off >>= 1) {
        s  += __shfl_down(s,  off);
        sq += __shfl_down(sq, off);
    }
    __shared__ float ps[4], pq[4];
    if (lane == 0) { ps[wave] = s; pq[wave] = sq; }
    __syncthreads();
    if (tid == 0) {
        const float S = ps[0] + ps[1] + ps[2] + ps[3];
        const float Q = pq[0] + pq[1] + pq[2] + pq[3];
        const float mean = S / (float)NT;
        const float var  = (Q - S * S / (float)NT) / (float)(NT - 1);
        const float sd   = sqrtf(fmaxf(var, 0.f));
        const int b = row >> 9;
        const int c = row & (NC - 1);
        stats[b * TWOC + c]      = mean;
        stats[b * TWOC + NC + c] = sd;
    }
}

// ---------------- Kernel 2a: h[b][j] = dot(stats[b,:], W1[j,:]) + b1[j] ----------------
// One wave per (j, group-of-4 b). 8192 waves = 2048 blocks.
__global__ __launch_bounds__(256) void h_kernel(const float* __restrict__ stats,
                                                const float* __restrict__ W1,
                                                const float* __restrict__ b1,
                                                float* __restrict__ hbuf) {
    const int wid  = blockIdx.x * 4 + (threadIdx.x >> 6);  // 0..8191
    const int lane = threadIdx.x & 63;
    const int j    = wid >> 4;          // 0..511
    const int b0   = (wid & 15) * 4;    // 0,4,...,60

    const float4* wr = (const float4*)(W1 + (size_t)j * TWOC);  // 256 float4
    const float4* s0p = (const float4*)(stats + (size_t)(b0 + 0) * TWOC);
    const float4* s1p = (const float4*)(stats + (size_t)(b0 + 1) * TWOC);
    const float4* s2p = (const float4*)(stats + (size_t)(b0 + 2) * TWOC);
    const float4* s3p = (const float4*)(stats + (size_t)(b0 + 3) * TWOC);

    float a0 = 0.f, a1 = 0.f, a2 = 0.f, a3 = 0.f;
    #pragma unroll
    for (int r = 0; r < 4; ++r) {
        const int i4 = r * 64 + lane;
        const float4 wv = wr[i4];
        const float4 v0 = s0p[i4];
        const float4 v1 = s1p[i4];
        const float4 v2 = s2p[i4];
        const float4 v3 = s3p[i4];
        a0 += wv.x*v0.x + wv.y*v0.y + wv.z*v0.z + wv.w*v0.w;
        a1 += wv.x*v1.x + wv.y*v1.y + wv.z*v1.z + wv.w*v1.w;
        a2 += wv.x*v2.x + wv.y*v2.y + wv.z*v2.z + wv.w*v2.w;
        a3 += wv.x*v3.x + wv.y*v3.y + wv.z*v3.z + wv.w*v3.w;
    }
    #pragma unroll
    for (int off = 32; off; off >>= 1) {
        a0 += __shfl_down(a0, off);
        a1 += __shfl_down(a1, off);
        a2 += __shfl_down(a2, off);
        a3 += __shfl_down(a3, off);
    }
    if (lane == 0) {
        const float bb = b1[j];
        hbuf[(size_t)(b0 + 0) * NH + j] = a0 + bb;
        hbuf[(size_t)(b0 + 1) * NH + j] = a1 + bb;
        hbuf[(size_t)(b0 + 2) * NH + j] = a2 + bb;
        hbuf[(size_t)(b0 + 3) * NH + j] = a3 + bb;
    }
}

// ---------------- Kernel 2b: s[b,k,c] = dot(h[b,:], W2[k,c,:]) + b2[k,c]; w = softmax_k ----------------
// One wave per (c, group-of-4 b). 8192 waves = 2048 blocks. Fused softmax.
__global__ __launch_bounds__(256) void sw_kernel(const float* __restrict__ hbuf,
                                                 const float* __restrict__ W2,
                                                 const float* __restrict__ b2,
                                                 float* __restrict__ wbuf) {
    const int wid  = blockIdx.x * 4 + (threadIdx.x >> 6);  // 0..8191
    const int lane = threadIdx.x & 63;
    const int c    = wid >> 4;          // 0..511
    const int b0   = (wid & 15) * 4;

    const float4* w0r = (const float4*)(W2 + ((size_t)(0 * NC + c)) * NH);  // 128 float4
    const float4* w1r = (const float4*)(W2 + ((size_t)(1 * NC + c)) * NH);
    const float4* w2r = (const float4*)(W2 + ((size_t)(2 * NC + c)) * NH);

    float acc00=0,acc01=0,acc02=0,acc03=0;
    float acc10=0,acc11=0,acc12=0,acc13=0;
    float acc20=0,acc21=0,acc22=0,acc23=0;

    #pragma unroll
    for (int r = 0; r < 2; ++r) {
        const int i4 = r * 64 + lane;
        const float4 w0v = w0r[i4];
        const float4 w1v = w1r[i4];
        const float4 w2v = w2r[i4];
        const float4 h0 = ((const float4*)(hbuf + (size_t)(b0 + 0) * NH))[i4];
        const float4 h1 = ((const float4*)(hbuf + (size_t)(b0 + 1) * NH))[i4];
        const float4 h2 = ((const float4*)(hbuf + (size_t)(b0 + 2) * NH))[i4];
        const float4 h3 = ((const float4*)(hbuf + (size_t)(b0 + 3) * NH))[i4];
        acc00 += w0v.x*h0.x + w0v.y*h0.y + w0v.z*h0.z + w0v.w*h0.w;
        acc01 += w0v.x*h1.x + w0v.y*h1.y + w0v.z*h1.z + w0v.w*h1.w;
        acc02 += w0v.x*h2.x + w0v.y*h2.y + w0v.z*h2.z + w0v.w*h2.w;
        acc03 += w0v.x*h3.x + w0v.y*h3.y + w0v.z*h3.z + w0v.w*h3.w;
        acc10 += w1v.x*h0.x + w1v.y*h0.y + w1v.z*h0.z + w1v.w*h0.w;
        acc11 += w1v.x*h1.x + w1v.y*h1.y + w1v.z*h1.z + w1v.w*h1.w;
        acc12 += w1v.x*h2.x + w1v.y*h2.y + w1v.z*h2.z + w1v.w*h2.w;
        acc13 += w1v.x*h3.x + w1v.y*h3.y + w1v.z*h3.z + w1v.w*h3.w;
        acc20 += w2v.x*h0.x + w2v.y*h0.y + w2v.z*h0.z + w2v.w*h0.w;
        acc21 += w2v.x*h1.x + w2v.y*h1.y + w2v.z*h1.z + w2v.w*h1.w;
        acc22 += w2v.x*h2.x + w2v.y*h2.y + w2v.z*h2.z + w2v.w*h2.w;
        acc23 += w2v.x*h3.x + w2v.y*h3.y + w2v.z*h3.z + w2v.w*h3.w;
    }
    #pragma unroll
    for (int off = 32; off; off >>= 1) {
        acc00 += __shfl_down(acc00, off); acc01 += __shfl_down(acc01, off);
        acc02 += __shfl_down(acc02, off); acc03 += __shfl_down(acc03, off);
        acc10 += __shfl_down(acc10, off); acc11 += __shfl_down(acc11, off);
        acc12 += __shfl_down(acc12, off); acc13 += __shfl_down(acc13, off);
        acc20 += __shfl_down(acc20, off); acc21 += __shfl_down(acc21, off);
        acc22 += __shfl_down(acc22, off); acc23 += __shfl_down(acc23, off);
    }
    if (lane == 0) {
        const float bb0 = b2[0 * NC + c];
        const float bb1 = b2[1 * NC + c];
        const float bb2 = b2[2 * NC + c];
        float v0[4] = {acc00 + bb0, acc01 + bb0, acc02 + bb0, acc03 + bb0};
        float v1[4] = {acc10 + bb1, acc11 + bb1, acc12 + bb1, acc13 + bb1};
        float v2[4] = {acc20 + bb2, acc21 + bb2, acc22 + bb2, acc23 + bb2};
        #pragma unroll
        for (int bb = 0; bb < 4; ++bb) {
            const float m  = fmaxf(v0[bb], fmaxf(v1[bb], v2[bb]));
            const float e0 = expf(v0[bb] - m);
            const float e1 = expf(v1[bb] - m);
            const float e2 = expf(v2[bb] - m);
            const float inv = 1.f / (e0 + e1 + e2);
            const size_t base = (size_t)(b0 + bb) * 3 * NC + c;
            wbuf[base + 0 * NC] = e0 * inv;
            wbuf[base + 1 * NC] = e1 * inv;
            wbuf[base + 2 * NC] = e2 * inv;
        }
    }
}

// ---------------- Kernel 3: out = w0*x0 + w1*x1 + w2*x2 ----------------
__global__ __launch_bounds__(256) void apply_kernel(const float* __restrict__ x0,
                                                    const float* __restrict__ x1,
                                                    const float* __restrict__ x2,
                                                    const float* __restrict__ wbuf,
                                                    float* __restrict__ out) {
    const int row = blockIdx.x;           // b*NC + c
    const int tid = threadIdx.x;
    if (tid >= NT4) return;
    const int b = row >> 9;
    const int c = row & (NC - 1);
    const float w0 = wbuf[((size_t)b * 3 + 0) * NC + c];
    const float w1 = wbuf[((size_t)b * 3 + 1) * NC + c];
    const float w2 = wbuf[((size_t)b * 3 + 2) * NC + c];
    const int idx = row * NT4 + tid;
    const float4 a = ((const float4*)x0)[idx];
    const float4 d = ((const float4*)x1)[idx];
    const float4 e = ((const float4*)x2)[idx];
    float4 r;
    r.x = a.x*w0 + d.x*w1 + e.x*w2;
    r.y = a.y*w0 + d.y*w1 + e.y*w2;
    r.z = a.z*w0 + d.z*w1 + e.z*w2;
    r.w = a.w*w0 + d.w*w1 + e.w*w2;
    ((float4*)out)[idx] = r;
}

extern "C" void kernel_launch(void* const* d_in, const int* in_sizes, int n_in,
                              void* d_out, int out_size, void* d_ws, size_t ws_size,
                              hipStream_t stream) {
    const float* x0 = (const float*)d_in[0];
    const float* x1 = (const float*)d_in[1];
    const float* x2 = (const float*)d_in[2];
    const float* W1 = (const float*)d_in[3];
    const float* b1 = (const float*)d_in[4];
    const float* W2 = (const float*)d_in[5];
    const float* b2 = (const float*)d_in[6];
    float* out = (float*)d_out;

    float* stats = (float*)d_ws;                 // NB*TWOC floats
    float* hbuf  = stats + NB * TWOC;            // NB*NH floats
    float* wbuf  = hbuf + NB * NH;               // NB*3*NC floats

    stats_kernel<<<NB * NC, 256, 0, stream>>>(x0, x1, x2, stats);
    h_kernel<<<2048, 256, 0, stream>>>(stats, W1, b1, hbuf);
    sw_kernel<<<2048, 256, 0, stream>>>(hbuf, W2, b2, wbuf);
    apply_kernel<<<NB * NC, 256, 0, stream>>>(x0, x1, x2, wbuf, out);
}